// Round 1
// baseline (1021.469 us; speedup 1.0000x reference)
//
#include <hip/hip_runtime.h>

// ---------------- tables ----------------
__constant__ int c_tri[16][6] = {
 {-1,-1,-1,-1,-1,-1},{1,0,2,-1,-1,-1},{4,0,3,-1,-1,-1},{1,4,2,1,3,4},
 {3,1,5,-1,-1,-1},{2,3,0,2,5,3},{1,4,0,1,5,4},{4,2,5,-1,-1,-1},
 {4,5,2,-1,-1,-1},{4,1,0,4,5,1},{3,2,0,3,5,2},{1,3,5,-1,-1,-1},
 {4,1,2,4,3,1},{3,0,4,-1,-1,-1},{2,0,1,-1,-1,-1},{-1,-1,-1,-1,-1,-1}};
__constant__ int c_ntri[16] = {0,1,1,2,1,2,2,1,1,2,2,1,2,1,1,0};
__constant__ int c_ea[6] = {0,0,0,1,1,2};
__constant__ int c_eb[6] = {1,2,3,2,3,3};

// ---------------- utility kernels ----------------
__global__ void k_zero_f32(float4* p, int n4) {
    int i = blockIdx.x * blockDim.x + threadIdx.x;
    int st = gridDim.x * blockDim.x;
    float4 z = {0.f, 0.f, 0.f, 0.f};
    for (; i < n4; i += st) p[i] = z;
}

__global__ void k_zero_u32(unsigned* p, int n) {
    int i = blockIdx.x * blockDim.x + threadIdx.x;
    int st = gridDim.x * blockDim.x;
    for (; i < n; i += st) p[i] = 0u;
}

__global__ void k_copy_u32(const unsigned* src, unsigned* dst, int n) {
    int i = blockIdx.x * blockDim.x + threadIdx.x;
    if (i < n) dst[i] = src[i];
}

// ---------------- scan (exclusive, n -> out[n+1]) ----------------
#define SBS 256
#define SIT 4

__global__ void k_scan1(const unsigned* in, unsigned* out, unsigned* bsum, int n) {
    __shared__ unsigned sm[SBS];
    int t = threadIdx.x, blk = blockIdx.x;
    int base = blk * SBS * SIT + t * SIT;
    unsigned v[SIT];
    unsigned tot = 0;
#pragma unroll
    for (int k = 0; k < SIT; k++) {
        v[k] = (base + k < n) ? in[base + k] : 0u;
        tot += v[k];
    }
    sm[t] = tot;
    __syncthreads();
    for (int off = 1; off < SBS; off <<= 1) {
        unsigned x = (t >= off) ? sm[t - off] : 0u;
        __syncthreads();
        sm[t] += x;
        __syncthreads();
    }
    unsigned run = (t == 0) ? 0u : sm[t - 1];
#pragma unroll
    for (int k = 0; k < SIT; k++) {
        if (base + k < n) out[base + k] = run;
        run += v[k];
    }
    if (t == SBS - 1) bsum[blk] = sm[SBS - 1];
}

__global__ void k_scan2(unsigned* bsum, unsigned* out, int nb, int n) {
    if (threadIdx.x == 0 && blockIdx.x == 0) {
        unsigned run = 0;
        for (int i = 0; i < nb; i++) {
            unsigned t = bsum[i];
            bsum[i] = run;
            run += t;
        }
        out[n] = run;  // grand total
    }
}

__global__ void k_scan3(unsigned* out, const unsigned* bsum, int n) {
    int t = threadIdx.x, blk = blockIdx.x;
    int base = blk * SBS * SIT + t * SIT;
    unsigned add = bsum[blk];
#pragma unroll
    for (int k = 0; k < SIT; k++) {
        if (base + k < n) out[base + k] += add;
    }
}

// ---------------- pipeline kernels ----------------
// count crossing edges per min-vertex bucket
__global__ void k_count(const int* __restrict__ tet, const float* __restrict__ sdf,
                        unsigned* __restrict__ h, int F) {
    int f = blockIdx.x * blockDim.x + threadIdx.x;
    if (f >= F) return;
    int4 tv = ((const int4*)tet)[f];
    int v[4] = {tv.x, tv.y, tv.z, tv.w};
    bool occ[4];
#pragma unroll
    for (int i = 0; i < 4; i++) occ[i] = sdf[v[i]] > 0.f;
#pragma unroll
    for (int j = 0; j < 6; j++) {
        int i0 = c_ea[j], i1 = c_eb[j];
        if (occ[i0] != occ[i1]) {
            int a = min(v[i0], v[i1]);
            atomicAdd(&h[a], 1u);
        }
    }
}

// scatter b values into bucket pools
__global__ void k_scatter(const int* __restrict__ tet, const float* __restrict__ sdf,
                          unsigned* __restrict__ cursor, unsigned* __restrict__ pool_b, int F) {
    int f = blockIdx.x * blockDim.x + threadIdx.x;
    if (f >= F) return;
    int4 tv = ((const int4*)tet)[f];
    int v[4] = {tv.x, tv.y, tv.z, tv.w};
    bool occ[4];
#pragma unroll
    for (int i = 0; i < 4; i++) occ[i] = sdf[v[i]] > 0.f;
#pragma unroll
    for (int j = 0; j < 6; j++) {
        int i0 = c_ea[j], i1 = c_eb[j];
        if (occ[i0] != occ[i1]) {
            int a = min(v[i0], v[i1]);
            int b = max(v[i0], v[i1]);
            unsigned pos = atomicAdd(&cursor[a], 1u);
            pool_b[pos] = (unsigned)b;
        }
    }
}

// per-bucket insertion sort + dedupe-compact
__global__ void k_bucket_sort(const unsigned* __restrict__ scat_base,
                              unsigned* __restrict__ pool_b,
                              unsigned* __restrict__ cnt, int N) {
    int a = blockIdx.x * blockDim.x + threadIdx.x;
    if (a >= N) return;
    unsigned s = scat_base[a];
    int m = (int)(scat_base[a + 1] - s);
    for (int i = 1; i < m; i++) {
        unsigned key = pool_b[s + i];
        int j = i - 1;
        while (j >= 0 && pool_b[s + j] > key) {
            pool_b[s + j + 1] = pool_b[s + j];
            j--;
        }
        pool_b[s + j + 1] = key;
    }
    int d = 0;
    unsigned prev = 0xFFFFFFFFu;
    for (int i = 0; i < m; i++) {
        unsigned b = pool_b[s + i];
        if (b != prev) {
            pool_b[s + d] = b;
            d++;
            prev = b;
        }
    }
    cnt[a] = (unsigned)d;
}

// write interpolated verts in key-sorted order
__global__ void k_verts(const float* __restrict__ pos, const float* __restrict__ sdf,
                        const unsigned* __restrict__ scat_base, const unsigned* __restrict__ cnt,
                        const unsigned* __restrict__ rank_base, const unsigned* __restrict__ pool_b,
                        float* __restrict__ verts, float* __restrict__ vvalid, int N) {
    int a = blockIdx.x * blockDim.x + threadIdx.x;
    if (a >= N) return;
    int d = (int)cnt[a];
    if (d == 0) return;
    unsigned s = scat_base[a];
    unsigned rb = rank_base[a];
    float sa = sdf[a];
    float pax = pos[(size_t)a * 3 + 0];
    float pay = pos[(size_t)a * 3 + 1];
    float paz = pos[(size_t)a * 3 + 2];
    for (int i = 0; i < d; i++) {
        unsigned b = pool_b[s + i];
        float sb = sdf[b];
        float denom = sa - sb;
        float w0 = (-sb) / denom;  // weight for pos[a] (ua = min)
        float w1 = sa / denom;     // weight for pos[b]
        size_t r = (size_t)(rb + i);
        verts[r * 3 + 0] = pax * w0 + pos[(size_t)b * 3 + 0] * w1;
        verts[r * 3 + 1] = pay * w0 + pos[(size_t)b * 3 + 1] * w1;
        verts[r * 3 + 2] = paz * w0 + pos[(size_t)b * 3 + 2] * w1;
        vvalid[r] = 1.0f;
    }
}

__device__ __forceinline__ float edge_rank(int A, int B,
                                           const unsigned* scat_base, const unsigned* cnt,
                                           const unsigned* rank_base, const unsigned* pool_b) {
    unsigned s = scat_base[A];
    int m = (int)cnt[A];
    int lo = 0, hi = m;
    unsigned ub = (unsigned)B;
    while (lo < hi) {
        int mid = (lo + hi) >> 1;
        if (pool_b[s + mid] < ub) lo = mid + 1;
        else hi = mid;
    }
    return (float)(rank_base[A] + (unsigned)lo);
}

// faces + face_valid (writes every slot -> deterministic)
__global__ void k_faces(const int* __restrict__ tet, const float* __restrict__ sdf,
                        const unsigned* __restrict__ scat_base, const unsigned* __restrict__ cnt,
                        const unsigned* __restrict__ rank_base, const unsigned* __restrict__ pool_b,
                        float* __restrict__ faces, float* __restrict__ fvalid, int F) {
    int f = blockIdx.x * blockDim.x + threadIdx.x;
    if (f >= F) return;
    int4 tv = ((const int4*)tet)[f];
    int v[4] = {tv.x, tv.y, tv.z, tv.w};
    bool occ[4];
#pragma unroll
    for (int i = 0; i < 4; i++) occ[i] = sdf[v[i]] > 0.f;
    int ti = (occ[0] ? 1 : 0) + (occ[1] ? 2 : 0) + (occ[2] ? 4 : 0) + (occ[3] ? 8 : 0);
    int nt = c_ntri[ti];

    float f0[3] = {-1.f, -1.f, -1.f};
    float f1[3] = {-1.f, -1.f, -1.f};
    if (nt >= 1) {
#pragma unroll
        for (int k = 0; k < 3; k++) {
            int e = c_tri[ti][k];
            int va = v[c_ea[e]], vb = v[c_eb[e]];
            int A = min(va, vb), B = max(va, vb);
            f0[k] = edge_rank(A, B, scat_base, cnt, rank_base, pool_b);
        }
    }
    if (nt == 2) {
#pragma unroll
        for (int k = 0; k < 3; k++) {
            int e = c_tri[ti][3 + k];
            int va = v[c_ea[e]], vb = v[c_eb[e]];
            int A = min(va, vb), B = max(va, vb);
            f1[k] = edge_rank(A, B, scat_base, cnt, rank_base, pool_b);
        }
    }
    size_t r0 = (size_t)f * 3;
    size_t r1 = ((size_t)F + f) * 3;
    faces[r0 + 0] = f0[0]; faces[r0 + 1] = f0[1]; faces[r0 + 2] = f0[2];
    faces[r1 + 0] = f1[0]; faces[r1 + 1] = f1[1]; faces[r1 + 2] = f1[2];
    fvalid[f] = (nt >= 1) ? 1.f : 0.f;
    fvalid[F + f] = (nt == 2) ? 1.f : 0.f;
}

// ---------------- host launch ----------------
static void run_scan(const unsigned* in, unsigned* out, unsigned* bsum, int n, hipStream_t stream) {
    int nb = (n + SBS * SIT - 1) / (SBS * SIT);
    k_scan1<<<nb, SBS, 0, stream>>>(in, out, bsum, n);
    k_scan2<<<1, 64, 0, stream>>>(bsum, out, nb, n);
    k_scan3<<<nb, SBS, 0, stream>>>(out, bsum, n);
}

extern "C" void kernel_launch(void* const* d_in, const int* in_sizes, int n_in,
                              void* d_out, int out_size, void* d_ws, size_t ws_size,
                              hipStream_t stream) {
    const float* pos = (const float*)d_in[0];
    const float* sdf = (const float*)d_in[1];
    const int* tet = (const int*)d_in[2];
    const int N = in_sizes[1];
    const int F = in_sizes[2] / 4;

    float* out = (float*)d_out;
    size_t nverts = (size_t)6 * F;           // vert rows
    size_t nfaces = (size_t)2 * F;           // face rows
    float* o_verts = out;                    // [6F,3]
    float* o_faces = out + nverts * 3;       // [2F,3]
    float* o_vvalid = o_faces + nfaces * 3;  // [6F]
    float* o_fvalid = o_vvalid + nverts;     // [2F]

    // workspace layout (u32)
    unsigned* w = (unsigned*)d_ws;
    unsigned* h = w;                    // N
    unsigned* scat_base = h + N;        // N+1
    unsigned* cursor = scat_base + N + 1;   // N
    unsigned* cnt = cursor + N;         // N
    unsigned* rank_base = cnt + N;      // N+1
    unsigned* bsum = rank_base + N + 1; // 4096
    unsigned* pool_b = bsum + 4096;     // 6F

    const int BS = 256;
    int gF = (F + BS - 1) / BS;
    int gN = (N + BS - 1) / BS;

    // 1. zero histograms + output vert regions (padded slots must be 0)
    k_zero_u32<<<gN, BS, 0, stream>>>(h, N);
    k_zero_u32<<<gN, BS, 0, stream>>>(cnt, N);
    k_zero_f32<<<2048, BS, 0, stream>>>((float4*)o_verts, (int)(nverts * 3 / 4));
    k_zero_f32<<<2048, BS, 0, stream>>>((float4*)o_vvalid, (int)(nverts / 4));

    // 2. count crossing edges per bucket
    k_count<<<gF, BS, 0, stream>>>(tet, sdf, h, F);

    // 3. scan -> scatter bases
    run_scan(h, scat_base, bsum, N, stream);

    // 4. cursors = scatter bases
    k_copy_u32<<<gN, BS, 0, stream>>>(scat_base, cursor, N);

    // 5. scatter b values
    k_scatter<<<gF, BS, 0, stream>>>(tet, sdf, cursor, pool_b, F);

    // 6. per-bucket sort + dedupe
    k_bucket_sort<<<gN, BS, 0, stream>>>(scat_base, pool_b, cnt, N);

    // 7. scan distinct counts -> global vert ranks
    run_scan(cnt, rank_base, bsum, N, stream);

    // 8. verts
    k_verts<<<gN, BS, 0, stream>>>(pos, sdf, scat_base, cnt, rank_base, pool_b,
                                   o_verts, o_vvalid, N);

    // 9. faces
    k_faces<<<gF, BS, 0, stream>>>(tet, sdf, scat_base, cnt, rank_base, pool_b,
                                   o_faces, o_fvalid, F);
}

// Round 2
// 856.551 us; speedup vs baseline: 1.1925x; 1.1925x over previous
//
#include <hip/hip_runtime.h>

// ---------------- tables ----------------
__constant__ int c_tri[16][6] = {
 {-1,-1,-1,-1,-1,-1},{1,0,2,-1,-1,-1},{4,0,3,-1,-1,-1},{1,4,2,1,3,4},
 {3,1,5,-1,-1,-1},{2,3,0,2,5,3},{1,4,0,1,5,4},{4,2,5,-1,-1,-1},
 {4,5,2,-1,-1,-1},{4,1,0,4,5,1},{3,2,0,3,5,2},{1,3,5,-1,-1,-1},
 {4,1,2,4,3,1},{3,0,4,-1,-1,-1},{2,0,1,-1,-1,-1},{-1,-1,-1,-1,-1,-1}};
__constant__ int c_ntri[16] = {0,1,1,2,1,2,2,1,1,2,2,1,2,1,1,0};
__constant__ int c_ea[6] = {0,0,0,1,1,2};
__constant__ int c_eb[6] = {1,2,3,2,3,3};

// ---------------- utility kernels ----------------
__global__ void k_zero_f32(float4* p, int n4) {
    int i = blockIdx.x * blockDim.x + threadIdx.x;
    int st = gridDim.x * blockDim.x;
    float4 z = {0.f, 0.f, 0.f, 0.f};
    for (; i < n4; i += st) p[i] = z;
}

__global__ void k_zero_u32(unsigned* p, int n) {
    int i = blockIdx.x * blockDim.x + threadIdx.x;
    int st = gridDim.x * blockDim.x;
    for (; i < n; i += st) p[i] = 0u;
}

__global__ void k_copy_u32(const unsigned* src, unsigned* dst, int n) {
    int i = blockIdx.x * blockDim.x + threadIdx.x;
    if (i < n) dst[i] = src[i];
}

// ---------------- scan (exclusive, n -> out[n+1]) ----------------
#define SBS 256
#define SIT 4

__global__ void k_scan1(const unsigned* in, unsigned* out, unsigned* bsum, int n) {
    __shared__ unsigned sm[SBS];
    int t = threadIdx.x, blk = blockIdx.x;
    int base = blk * SBS * SIT + t * SIT;
    unsigned v[SIT];
    unsigned tot = 0;
#pragma unroll
    for (int k = 0; k < SIT; k++) {
        v[k] = (base + k < n) ? in[base + k] : 0u;
        tot += v[k];
    }
    sm[t] = tot;
    __syncthreads();
    for (int off = 1; off < SBS; off <<= 1) {
        unsigned x = (t >= off) ? sm[t - off] : 0u;
        __syncthreads();
        sm[t] += x;
        __syncthreads();
    }
    unsigned run = (t == 0) ? 0u : sm[t - 1];
#pragma unroll
    for (int k = 0; k < SIT; k++) {
        if (base + k < n) out[base + k] = run;
        run += v[k];
    }
    if (t == SBS - 1) bsum[blk] = sm[SBS - 1];
}

__global__ void k_scan2(unsigned* bsum, unsigned* out, int nb, int n) {
    if (threadIdx.x == 0 && blockIdx.x == 0) {
        unsigned run = 0;
        for (int i = 0; i < nb; i++) {
            unsigned t = bsum[i];
            bsum[i] = run;
            run += t;
        }
        out[n] = run;  // grand total
    }
}

__global__ void k_scan3(unsigned* out, const unsigned* bsum, int n) {
    int t = threadIdx.x, blk = blockIdx.x;
    int base = blk * SBS * SIT + t * SIT;
    unsigned add = bsum[blk];
#pragma unroll
    for (int k = 0; k < SIT; k++) {
        if (base + k < n) out[base + k] += add;
    }
}

// ---------------- pipeline kernels ----------------
// count crossing edges per min-vertex bucket
__global__ void k_count(const int* __restrict__ tet, const float* __restrict__ sdf,
                        unsigned* __restrict__ h, int F) {
    int f = blockIdx.x * blockDim.x + threadIdx.x;
    if (f >= F) return;
    int4 tv = ((const int4*)tet)[f];
    int v[4] = {tv.x, tv.y, tv.z, tv.w};
    bool occ[4];
#pragma unroll
    for (int i = 0; i < 4; i++) occ[i] = sdf[v[i]] > 0.f;
#pragma unroll
    for (int j = 0; j < 6; j++) {
        int i0 = c_ea[j], i1 = c_eb[j];
        if (occ[i0] != occ[i1]) {
            int a = min(v[i0], v[i1]);
            atomicAdd(&h[a], 1u);
        }
    }
}

// scatter b values into bucket pools
__global__ void k_scatter(const int* __restrict__ tet, const float* __restrict__ sdf,
                          unsigned* __restrict__ cursor, unsigned* __restrict__ pool_b, int F) {
    int f = blockIdx.x * blockDim.x + threadIdx.x;
    if (f >= F) return;
    int4 tv = ((const int4*)tet)[f];
    int v[4] = {tv.x, tv.y, tv.z, tv.w};
    bool occ[4];
#pragma unroll
    for (int i = 0; i < 4; i++) occ[i] = sdf[v[i]] > 0.f;
#pragma unroll
    for (int j = 0; j < 6; j++) {
        int i0 = c_ea[j], i1 = c_eb[j];
        if (occ[i0] != occ[i1]) {
            int a = min(v[i0], v[i1]);
            int b = max(v[i0], v[i1]);
            unsigned pos = atomicAdd(&cursor[a], 1u);
            pool_b[pos] = (unsigned)b;
        }
    }
}

// wave-per-bucket: bitonic sort in registers + shuffle dedupe-compact
__global__ void k_bucket_sort(const unsigned* __restrict__ scat_base,
                              unsigned* __restrict__ pool_b,
                              unsigned* __restrict__ cnt, int N) {
    int wave = (blockIdx.x * blockDim.x + threadIdx.x) >> 6;
    int lane = threadIdx.x & 63;
    if (wave >= N) return;
    unsigned s = scat_base[wave];
    int m = (int)(scat_base[wave + 1] - s);
    if (m <= 64) {
        unsigned v = (lane < m) ? pool_b[s + lane] : 0xFFFFFFFFu;
        // bitonic sort of 64 values, one per lane, via shfl_xor
#pragma unroll
        for (int k = 2; k <= 64; k <<= 1) {
#pragma unroll
            for (int j = k >> 1; j >= 1; j >>= 1) {
                unsigned partner = __shfl_xor(v, j, 64);
                bool takeMin = (((lane & k) == 0) == ((lane & j) == 0));
                unsigned mn = min(v, partner), mx = max(v, partner);
                v = takeMin ? mn : mx;
            }
        }
        // dedupe: valid values (< 0xFFFFFFFF since b < N) now at lanes [0,m)
        unsigned prev = __shfl_up(v, 1, 64);
        bool uniq = (lane < m) && (lane == 0 || v != prev);
        unsigned long long mask = __ballot(uniq);
        if (uniq) {
            int pos = __popcll(mask & ((1ULL << lane) - 1ULL));
            pool_b[s + pos] = v;
        }
        if (lane == 0) cnt[wave] = (unsigned)__popcll(mask);
    } else {
        // rare fallback: serial insertion sort + dedupe by lane 0
        if (lane == 0) {
            for (int i = 1; i < m; i++) {
                unsigned key = pool_b[s + i];
                int j = i - 1;
                while (j >= 0 && pool_b[s + j] > key) {
                    pool_b[s + j + 1] = pool_b[s + j];
                    j--;
                }
                pool_b[s + j + 1] = key;
            }
            int d = 0;
            unsigned prev = 0xFFFFFFFFu;
            for (int i = 0; i < m; i++) {
                unsigned b = pool_b[s + i];
                if (b != prev) {
                    pool_b[s + d] = b;
                    d++;
                    prev = b;
                }
            }
            cnt[wave] = (unsigned)d;
        }
    }
}

// write interpolated verts in key-sorted order
__global__ void k_verts(const float* __restrict__ pos, const float* __restrict__ sdf,
                        const unsigned* __restrict__ scat_base, const unsigned* __restrict__ cnt,
                        const unsigned* __restrict__ rank_base, const unsigned* __restrict__ pool_b,
                        float* __restrict__ verts, float* __restrict__ vvalid, int N) {
    int a = blockIdx.x * blockDim.x + threadIdx.x;
    if (a >= N) return;
    int d = (int)cnt[a];
    if (d == 0) return;
    unsigned s = scat_base[a];
    unsigned rb = rank_base[a];
    float sa = sdf[a];
    float pax = pos[(size_t)a * 3 + 0];
    float pay = pos[(size_t)a * 3 + 1];
    float paz = pos[(size_t)a * 3 + 2];
    for (int i = 0; i < d; i++) {
        unsigned b = pool_b[s + i];
        float sb = sdf[b];
        float denom = sa - sb;
        float w0 = (-sb) / denom;  // weight for pos[a] (ua = min)
        float w1 = sa / denom;     // weight for pos[b]
        size_t r = (size_t)(rb + i);
        verts[r * 3 + 0] = pax * w0 + pos[(size_t)b * 3 + 0] * w1;
        verts[r * 3 + 1] = pay * w0 + pos[(size_t)b * 3 + 1] * w1;
        verts[r * 3 + 2] = paz * w0 + pos[(size_t)b * 3 + 2] * w1;
        vvalid[r] = 1.0f;
    }
}

// lower_bound over the full bucket span: identical result to deduped prefix,
// since everything below the match is strictly smaller and the stale tail >= it.
__device__ __forceinline__ float edge_rank(int A, int B,
                                           const unsigned* scat_base,
                                           const unsigned* rank_base,
                                           const unsigned* pool_b) {
    unsigned s = scat_base[A];
    int m = (int)(scat_base[A + 1] - s);
    int lo = 0, hi = m;
    unsigned ub = (unsigned)B;
    while (lo < hi) {
        int mid = (lo + hi) >> 1;
        if (pool_b[s + mid] < ub) lo = mid + 1;
        else hi = mid;
    }
    return (float)(rank_base[A] + (unsigned)lo);
}

// faces + face_valid (writes every slot -> deterministic)
__global__ void k_faces(const int* __restrict__ tet, const float* __restrict__ sdf,
                        const unsigned* __restrict__ scat_base,
                        const unsigned* __restrict__ rank_base, const unsigned* __restrict__ pool_b,
                        float* __restrict__ faces, float* __restrict__ fvalid, int F) {
    int f = blockIdx.x * blockDim.x + threadIdx.x;
    if (f >= F) return;
    int4 tv = ((const int4*)tet)[f];
    int v[4] = {tv.x, tv.y, tv.z, tv.w};
    bool occ[4];
#pragma unroll
    for (int i = 0; i < 4; i++) occ[i] = sdf[v[i]] > 0.f;
    int ti = (occ[0] ? 1 : 0) + (occ[1] ? 2 : 0) + (occ[2] ? 4 : 0) + (occ[3] ? 8 : 0);
    int nt = c_ntri[ti];

    float f0[3] = {-1.f, -1.f, -1.f};
    float f1[3] = {-1.f, -1.f, -1.f};
    if (nt >= 1) {
#pragma unroll
        for (int k = 0; k < 3; k++) {
            int e = c_tri[ti][k];
            int va = v[c_ea[e]], vb = v[c_eb[e]];
            int A = min(va, vb), B = max(va, vb);
            f0[k] = edge_rank(A, B, scat_base, rank_base, pool_b);
        }
    }
    if (nt == 2) {
#pragma unroll
        for (int k = 0; k < 3; k++) {
            int e = c_tri[ti][3 + k];
            int va = v[c_ea[e]], vb = v[c_eb[e]];
            int A = min(va, vb), B = max(va, vb);
            f1[k] = edge_rank(A, B, scat_base, rank_base, pool_b);
        }
    }
    size_t r0 = (size_t)f * 3;
    size_t r1 = ((size_t)F + f) * 3;
    faces[r0 + 0] = f0[0]; faces[r0 + 1] = f0[1]; faces[r0 + 2] = f0[2];
    faces[r1 + 0] = f1[0]; faces[r1 + 1] = f1[1]; faces[r1 + 2] = f1[2];
    fvalid[f] = (nt >= 1) ? 1.f : 0.f;
    fvalid[F + f] = (nt == 2) ? 1.f : 0.f;
}

// ---------------- host launch ----------------
static void run_scan(const unsigned* in, unsigned* out, unsigned* bsum, int n, hipStream_t stream) {
    int nb = (n + SBS * SIT - 1) / (SBS * SIT);
    k_scan1<<<nb, SBS, 0, stream>>>(in, out, bsum, n);
    k_scan2<<<1, 64, 0, stream>>>(bsum, out, nb, n);
    k_scan3<<<nb, SBS, 0, stream>>>(out, bsum, n);
}

extern "C" void kernel_launch(void* const* d_in, const int* in_sizes, int n_in,
                              void* d_out, int out_size, void* d_ws, size_t ws_size,
                              hipStream_t stream) {
    const float* pos = (const float*)d_in[0];
    const float* sdf = (const float*)d_in[1];
    const int* tet = (const int*)d_in[2];
    const int N = in_sizes[1];
    const int F = in_sizes[2] / 4;

    float* out = (float*)d_out;
    size_t nverts = (size_t)6 * F;           // vert rows
    size_t nfaces = (size_t)2 * F;           // face rows
    float* o_verts = out;                    // [6F,3]
    float* o_faces = out + nverts * 3;       // [2F,3]
    float* o_vvalid = o_faces + nfaces * 3;  // [6F]
    float* o_fvalid = o_vvalid + nverts;     // [2F]

    // workspace layout (u32)
    unsigned* w = (unsigned*)d_ws;
    unsigned* h = w;                    // N
    unsigned* scat_base = h + N;        // N+1
    unsigned* cursor = scat_base + N + 1;   // N
    unsigned* cnt = cursor + N;         // N
    unsigned* rank_base = cnt + N;      // N+1
    unsigned* bsum = rank_base + N + 1; // 4096
    unsigned* pool_b = bsum + 4096;     // 6F

    const int BS = 256;
    int gF = (F + BS - 1) / BS;
    int gN = (N + BS - 1) / BS;

    // 1. zero histogram + output vert regions (padded slots must be 0)
    k_zero_u32<<<gN, BS, 0, stream>>>(h, N);
    k_zero_f32<<<2048, BS, 0, stream>>>((float4*)o_verts, (int)(nverts * 3 / 4));
    k_zero_f32<<<2048, BS, 0, stream>>>((float4*)o_vvalid, (int)(nverts / 4));

    // 2. count crossing edges per bucket
    k_count<<<gF, BS, 0, stream>>>(tet, sdf, h, F);

    // 3. scan -> scatter bases
    run_scan(h, scat_base, bsum, N, stream);

    // 4. cursors = scatter bases
    k_copy_u32<<<gN, BS, 0, stream>>>(scat_base, cursor, N);

    // 5. scatter b values
    k_scatter<<<gF, BS, 0, stream>>>(tet, sdf, cursor, pool_b, F);

    // 6. wave-per-bucket sort + dedupe
    k_bucket_sort<<<(N + 3) / 4, BS, 0, stream>>>(scat_base, pool_b, cnt, N);

    // 7. scan distinct counts -> global vert ranks
    run_scan(cnt, rank_base, bsum, N, stream);

    // 8. verts
    k_verts<<<gN, BS, 0, stream>>>(pos, sdf, scat_base, cnt, rank_base, pool_b,
                                   o_verts, o_vvalid, N);

    // 9. faces
    k_faces<<<gF, BS, 0, stream>>>(tet, sdf, scat_base, rank_base, pool_b,
                                   o_faces, o_fvalid, F);
}

// Round 3
// 815.456 us; speedup vs baseline: 1.2526x; 1.0504x over previous
//
#include <hip/hip_runtime.h>

// ---------------- tables ----------------
__constant__ int c_tri[16][6] = {
 {-1,-1,-1,-1,-1,-1},{1,0,2,-1,-1,-1},{4,0,3,-1,-1,-1},{1,4,2,1,3,4},
 {3,1,5,-1,-1,-1},{2,3,0,2,5,3},{1,4,0,1,5,4},{4,2,5,-1,-1,-1},
 {4,5,2,-1,-1,-1},{4,1,0,4,5,1},{3,2,0,3,5,2},{1,3,5,-1,-1,-1},
 {4,1,2,4,3,1},{3,0,4,-1,-1,-1},{2,0,1,-1,-1,-1},{-1,-1,-1,-1,-1,-1}};
__constant__ int c_ntri[16] = {0,1,1,2,1,2,2,1,1,2,2,1,2,1,1,0};
__constant__ int c_ea[6] = {0,0,0,1,1,2};
__constant__ int c_eb[6] = {1,2,3,2,3,3};

// ---------------- utility kernels ----------------
__global__ void k_zero_f32(float4* p, int n4) {
    int i = blockIdx.x * blockDim.x + threadIdx.x;
    int st = gridDim.x * blockDim.x;
    float4 z = {0.f, 0.f, 0.f, 0.f};
    for (; i < n4; i += st) p[i] = z;
}

__global__ void k_zero_u32(unsigned* p, int n) {
    int i = blockIdx.x * blockDim.x + threadIdx.x;
    int st = gridDim.x * blockDim.x;
    for (; i < n; i += st) p[i] = 0u;
}

__global__ void k_copy_u32(const unsigned* src, unsigned* dst, int n) {
    int i = blockIdx.x * blockDim.x + threadIdx.x;
    if (i < n) dst[i] = src[i];
}

// ---------------- scan (exclusive, n -> out[n+1]) ----------------
#define SBS 256
#define SIT 4

__global__ void k_scan1(const unsigned* in, unsigned* out, unsigned* bsum, int n) {
    __shared__ unsigned sm[SBS];
    int t = threadIdx.x, blk = blockIdx.x;
    int base = blk * SBS * SIT + t * SIT;
    unsigned v[SIT];
    unsigned tot = 0;
#pragma unroll
    for (int k = 0; k < SIT; k++) {
        v[k] = (base + k < n) ? in[base + k] : 0u;
        tot += v[k];
    }
    sm[t] = tot;
    __syncthreads();
    for (int off = 1; off < SBS; off <<= 1) {
        unsigned x = (t >= off) ? sm[t - off] : 0u;
        __syncthreads();
        sm[t] += x;
        __syncthreads();
    }
    unsigned run = (t == 0) ? 0u : sm[t - 1];
#pragma unroll
    for (int k = 0; k < SIT; k++) {
        if (base + k < n) out[base + k] = run;
        run += v[k];
    }
    if (t == SBS - 1) bsum[blk] = sm[SBS - 1];
}

__global__ void k_scan2(unsigned* bsum, unsigned* out, int nb, int n) {
    if (threadIdx.x == 0 && blockIdx.x == 0) {
        unsigned run = 0;
        for (int i = 0; i < nb; i++) {
            unsigned t = bsum[i];
            bsum[i] = run;
            run += t;
        }
        out[n] = run;  // grand total
    }
}

__global__ void k_scan3(unsigned* out, const unsigned* bsum, int n) {
    int t = threadIdx.x, blk = blockIdx.x;
    int base = blk * SBS * SIT + t * SIT;
    unsigned add = bsum[blk];
#pragma unroll
    for (int k = 0; k < SIT; k++) {
        if (base + k < n) out[base + k] += add;
    }
}

// ---------------- pipeline kernels ----------------
__global__ void k_count(const int* __restrict__ tet, const float* __restrict__ sdf,
                        unsigned* __restrict__ h, int F) {
    int f = blockIdx.x * blockDim.x + threadIdx.x;
    if (f >= F) return;
    int4 tv = ((const int4*)tet)[f];
    int v[4] = {tv.x, tv.y, tv.z, tv.w};
    bool occ[4];
#pragma unroll
    for (int i = 0; i < 4; i++) occ[i] = sdf[v[i]] > 0.f;
#pragma unroll
    for (int j = 0; j < 6; j++) {
        int i0 = c_ea[j], i1 = c_eb[j];
        if (occ[i0] != occ[i1]) {
            int a = min(v[i0], v[i1]);
            atomicAdd(&h[a], 1u);
        }
    }
}

// scatter b values + edge-slot payload into bucket pools
__global__ void k_scatter(const int* __restrict__ tet, const float* __restrict__ sdf,
                          unsigned* __restrict__ cursor, unsigned* __restrict__ pool_b,
                          unsigned* __restrict__ pool_e, int F) {
    int f = blockIdx.x * blockDim.x + threadIdx.x;
    if (f >= F) return;
    int4 tv = ((const int4*)tet)[f];
    int v[4] = {tv.x, tv.y, tv.z, tv.w};
    bool occ[4];
#pragma unroll
    for (int i = 0; i < 4; i++) occ[i] = sdf[v[i]] > 0.f;
#pragma unroll
    for (int j = 0; j < 6; j++) {
        int i0 = c_ea[j], i1 = c_eb[j];
        if (occ[i0] != occ[i1]) {
            int a = min(v[i0], v[i1]);
            int b = max(v[i0], v[i1]);
            unsigned pos = atomicAdd(&cursor[a], 1u);
            pool_b[pos] = (unsigned)b;
            pool_e[pos] = (unsigned)(f * 6 + j);
        }
    }
}

// ---- bucket sort helpers: key = (b<<6)|origin_lane (b < 2^18 so fits) ----

// full-wave 64-wide sort of one bucket (m <= 64)
__device__ __forceinline__ void sort_full_bucket(
    unsigned s, int m, int bucket, int lane,
    unsigned* __restrict__ pool_b, const unsigned* __restrict__ pool_e,
    unsigned* __restrict__ idx_map, unsigned* __restrict__ cnt) {
    unsigned key = (lane < m) ? ((pool_b[s + lane] << 6) | (unsigned)lane)
                              : (0xFFFFFFC0u | (unsigned)lane);
#pragma unroll
    for (int k = 2; k <= 64; k <<= 1) {
#pragma unroll
        for (int j = k >> 1; j >= 1; j >>= 1) {
            unsigned partner = __shfl_xor(key, j, 64);
            bool takeMin = (((lane & k) == 0) == ((lane & j) == 0));
            unsigned mn = min(key, partner), mx = max(key, partner);
            key = takeMin ? mn : mx;
        }
    }
    unsigned v = key >> 6;
    unsigned pv = __shfl_up(key, 1, 64) >> 6;
    bool valid = lane < m;  // sorted: valid elements occupy lanes [0,m)
    bool uniq = valid && (lane == 0 || v != pv);
    unsigned long long um = __ballot(uniq);
    if (uniq) {
        int pos = __popcll(um & ((1ull << lane) - 1ull));
        pool_b[s + pos] = v;
    }
    int urank = __popcll(um & ~(0xFFFFFFFFFFFFFFFEull << lane)) - 1;
    // push my value's unique-rank back to the origin lane (pure permutation)
    int recv = __builtin_amdgcn_ds_permute((int)((key & 63u) << 2), urank);
    if (valid) idx_map[pool_e[s + lane]] = (unsigned)recv;
    if (lane == 0) cnt[bucket] = (unsigned)__popcll(um);
}

// two buckets (each m <= 32) sorted simultaneously in the two 32-lane halves
__device__ __forceinline__ void sort_pair_bucket(
    unsigned s_a, int m_a, int ba, unsigned s_b, int m_b, int bb, int N, int lane,
    unsigned* __restrict__ pool_b, const unsigned* __restrict__ pool_e,
    unsigned* __restrict__ idx_map, unsigned* __restrict__ cnt) {
    int half = lane >> 5, hl = lane & 31;
    unsigned s = half ? s_b : s_a;
    int m = half ? m_b : m_a;
    unsigned key = (hl < m) ? ((pool_b[s + hl] << 6) | (unsigned)lane)
                            : (0xFFFFFFC0u | (unsigned)lane);
#pragma unroll
    for (int k = 2; k <= 32; k <<= 1) {
#pragma unroll
        for (int j = k >> 1; j >= 1; j >>= 1) {
            unsigned partner = __shfl_xor(key, j, 64);  // j<=16 stays in half
            bool takeMin = (((hl & k) == 0) == ((hl & j) == 0));
            unsigned mn = min(key, partner), mx = max(key, partner);
            key = takeMin ? mn : mx;
        }
    }
    unsigned v = key >> 6;
    unsigned pv = __shfl_up(key, 1, 64) >> 6;
    bool valid = hl < m;
    bool uniq = valid && (hl == 0 || v != pv);
    unsigned long long um_all = __ballot(uniq);
    unsigned um = (unsigned)(um_all >> (half ? 32 : 0));
    if (uniq) {
        int pos = __popc(um & ((1u << hl) - 1u));
        pool_b[s + pos] = v;
    }
    int urank = __popc(um & ~(0xFFFFFFFEu << hl)) - 1;
    int recv = __builtin_amdgcn_ds_permute((int)((key & 63u) << 2), urank);
    if (valid) idx_map[pool_e[s + hl]] = (unsigned)recv;
    if (hl == 0) {
        int bkt = half ? bb : ba;
        if (bkt < N) cnt[bkt] = (unsigned)__popc(um);
    }
}

// rare fallback m > 64: lane-0 serial sort (co-moves payload), ranks + compact
__device__ __forceinline__ void serial_bucket(
    unsigned s, int m, int bucket, int lane,
    unsigned* __restrict__ pool_b, unsigned* __restrict__ pool_e,
    unsigned* __restrict__ idx_map, unsigned* __restrict__ cnt) {
    if (lane != 0) return;
    for (int i = 1; i < m; i++) {
        unsigned kv = pool_b[s + i], ke = pool_e[s + i];
        int j = i - 1;
        while (j >= 0 && pool_b[s + j] > kv) {
            pool_b[s + j + 1] = pool_b[s + j];
            pool_e[s + j + 1] = pool_e[s + j];
            j--;
        }
        pool_b[s + j + 1] = kv;
        pool_e[s + j + 1] = ke;
    }
    int d = 0;
    unsigned prev = 0xFFFFFFFFu;
    for (int i = 0; i < m; i++) {
        unsigned bv = pool_b[s + i];
        if (bv != prev) { d++; prev = bv; pool_b[s + d - 1] = bv; }
        idx_map[pool_e[s + i]] = (unsigned)(d - 1);
    }
    cnt[bucket] = (unsigned)d;
}

// wave handles 4 consecutive buckets
__global__ void k_bucket_sort(const unsigned* __restrict__ scat_base,
                              unsigned* __restrict__ pool_b,
                              unsigned* __restrict__ pool_e,
                              unsigned* __restrict__ idx_map,
                              unsigned* __restrict__ cnt, int N) {
    int wid = (int)((blockIdx.x * blockDim.x + threadIdx.x) >> 6);
    int lane = threadIdx.x & 63;
    int b0 = wid * 4;
    if (b0 >= N) return;
    unsigned sb[5];
#pragma unroll
    for (int i = 0; i < 5; i++) sb[i] = scat_base[min(b0 + i, N)];
#pragma unroll
    for (int p = 0; p < 2; p++) {
        int ba = b0 + 2 * p, bb = ba + 1;
        if (ba >= N) break;
        unsigned s_a = sb[2 * p];
        int m_a = (int)(sb[2 * p + 1] - sb[2 * p]);
        unsigned s_b = sb[2 * p + 1];
        int m_b = (int)(sb[2 * p + 2] - sb[2 * p + 1]);
        if (m_a <= 32 && m_b <= 32) {
            sort_pair_bucket(s_a, m_a, ba, s_b, m_b, bb, N, lane,
                             pool_b, pool_e, idx_map, cnt);
        } else {
            if (m_a <= 64) sort_full_bucket(s_a, m_a, ba, lane, pool_b, pool_e, idx_map, cnt);
            else           serial_bucket(s_a, m_a, ba, lane, pool_b, pool_e, idx_map, cnt);
            if (bb < N) {
                if (m_b <= 64) sort_full_bucket(s_b, m_b, bb, lane, pool_b, pool_e, idx_map, cnt);
                else           serial_bucket(s_b, m_b, bb, lane, pool_b, pool_e, idx_map, cnt);
            }
        }
    }
}

// wave-per-bucket vert writer (lane-per-element)
__global__ void k_verts(const float* __restrict__ pos, const float* __restrict__ sdf,
                        const unsigned* __restrict__ scat_base, const unsigned* __restrict__ cnt,
                        const unsigned* __restrict__ rank_base, const unsigned* __restrict__ pool_b,
                        float* __restrict__ verts, float* __restrict__ vvalid, int N) {
    int a = (int)((blockIdx.x * blockDim.x + threadIdx.x) >> 6);
    int lane = threadIdx.x & 63;
    if (a >= N) return;
    int d = (int)cnt[a];
    unsigned s = scat_base[a];
    unsigned rb = rank_base[a];
    float sa = sdf[a];
    float pax = pos[(size_t)a * 3 + 0];
    float pay = pos[(size_t)a * 3 + 1];
    float paz = pos[(size_t)a * 3 + 2];
    for (int i = lane; i < d; i += 64) {
        unsigned b = pool_b[s + i];
        float sbv = sdf[b];
        float denom = sa - sbv;
        float w0 = (-sbv) / denom;
        float w1 = sa / denom;
        size_t r = (size_t)(rb + i);
        verts[r * 3 + 0] = pax * w0 + pos[(size_t)b * 3 + 0] * w1;
        verts[r * 3 + 1] = pay * w0 + pos[(size_t)b * 3 + 1] * w1;
        verts[r * 3 + 2] = paz * w0 + pos[(size_t)b * 3 + 2] * w1;
        vvalid[r] = 1.0f;
    }
}

// faces: rank = rank_base[min-vert] + idx_map[edge slot]; no searches
__global__ void k_faces(const int* __restrict__ tet, const float* __restrict__ sdf,
                        const unsigned* __restrict__ rank_base,
                        const unsigned* __restrict__ idx_map,
                        float* __restrict__ faces, float* __restrict__ fvalid, int F) {
    int f = blockIdx.x * blockDim.x + threadIdx.x;
    if (f >= F) return;
    int4 tv = ((const int4*)tet)[f];
    int v[4] = {tv.x, tv.y, tv.z, tv.w};
    bool occ[4];
#pragma unroll
    for (int i = 0; i < 4; i++) occ[i] = sdf[v[i]] > 0.f;
    int ti = (occ[0] ? 1 : 0) + (occ[1] ? 2 : 0) + (occ[2] ? 4 : 0) + (occ[3] ? 8 : 0);
    int nt = c_ntri[ti];

    float f0[3] = {-1.f, -1.f, -1.f};
    float f1[3] = {-1.f, -1.f, -1.f};
    if (nt >= 1) {
#pragma unroll
        for (int k = 0; k < 3; k++) {
            int e = c_tri[ti][k];
            int A = min(v[c_ea[e]], v[c_eb[e]]);
            f0[k] = (float)(rank_base[A] + idx_map[f * 6 + e]);
        }
    }
    if (nt == 2) {
#pragma unroll
        for (int k = 0; k < 3; k++) {
            int e = c_tri[ti][3 + k];
            int A = min(v[c_ea[e]], v[c_eb[e]]);
            f1[k] = (float)(rank_base[A] + idx_map[f * 6 + e]);
        }
    }
    size_t r0 = (size_t)f * 3;
    size_t r1 = ((size_t)F + f) * 3;
    faces[r0 + 0] = f0[0]; faces[r0 + 1] = f0[1]; faces[r0 + 2] = f0[2];
    faces[r1 + 0] = f1[0]; faces[r1 + 1] = f1[1]; faces[r1 + 2] = f1[2];
    fvalid[f] = (nt >= 1) ? 1.f : 0.f;
    fvalid[F + f] = (nt == 2) ? 1.f : 0.f;
}

// ---------------- host launch ----------------
static void run_scan(const unsigned* in, unsigned* out, unsigned* bsum, int n, hipStream_t stream) {
    int nb = (n + SBS * SIT - 1) / (SBS * SIT);
    k_scan1<<<nb, SBS, 0, stream>>>(in, out, bsum, n);
    k_scan2<<<1, 64, 0, stream>>>(bsum, out, nb, n);
    k_scan3<<<nb, SBS, 0, stream>>>(out, bsum, n);
}

extern "C" void kernel_launch(void* const* d_in, const int* in_sizes, int n_in,
                              void* d_out, int out_size, void* d_ws, size_t ws_size,
                              hipStream_t stream) {
    const float* pos = (const float*)d_in[0];
    const float* sdf = (const float*)d_in[1];
    const int* tet = (const int*)d_in[2];
    const int N = in_sizes[1];
    const int F = in_sizes[2] / 4;
    const int E = F * 6;

    float* out = (float*)d_out;
    size_t nverts = (size_t)6 * F;
    size_t nfaces = (size_t)2 * F;
    float* o_verts = out;                    // [6F,3]
    float* o_faces = out + nverts * 3;       // [2F,3]
    float* o_vvalid = o_faces + nfaces * 3;  // [6F]
    float* o_fvalid = o_vvalid + nverts;     // [2F]

    // workspace layout (u32): ~ (5N + 3E + 4k) * 4 bytes ≈ 80 MB
    unsigned* w = (unsigned*)d_ws;
    unsigned* h = w;                        // N
    unsigned* scat_base = h + N;            // N+1
    unsigned* cursor = scat_base + N + 1;   // N
    unsigned* cnt = cursor + N;             // N
    unsigned* rank_base = cnt + N;          // N+1
    unsigned* bsum = rank_base + N + 1;     // 4096
    unsigned* pool_b = bsum + 4096;         // E
    unsigned* pool_e = pool_b + E;          // E
    unsigned* idx_map = pool_e + E;         // E

    const int BS = 256;
    int gF = (F + BS - 1) / BS;
    int gN = (N + BS - 1) / BS;
    int gW = (N + 3) / 4;        // blocks for wave-per-bucket (4 waves/block)
    int gW4 = (N + 15) / 16;     // blocks for wave-per-4-buckets

    // 1. zero histogram + padded output vert regions
    k_zero_u32<<<gN, BS, 0, stream>>>(h, N);
    k_zero_f32<<<2048, BS, 0, stream>>>((float4*)o_verts, (int)(nverts * 3 / 4));
    k_zero_f32<<<2048, BS, 0, stream>>>((float4*)o_vvalid, (int)(nverts / 4));

    // 2. count crossing edges per bucket
    k_count<<<gF, BS, 0, stream>>>(tet, sdf, h, F);

    // 3. scan -> scatter bases
    run_scan(h, scat_base, bsum, N, stream);

    // 4. cursors = scatter bases
    k_copy_u32<<<gN, BS, 0, stream>>>(scat_base, cursor, N);

    // 5. scatter (b, edge-slot)
    k_scatter<<<gF, BS, 0, stream>>>(tet, sdf, cursor, pool_b, pool_e, F);

    // 6. size-adaptive bucket sort + dedupe + rank scatter-back
    k_bucket_sort<<<gW4, BS, 0, stream>>>(scat_base, pool_b, pool_e, idx_map, cnt, N);

    // 7. scan distinct counts -> global vert ranks
    run_scan(cnt, rank_base, bsum, N, stream);

    // 8. verts (wave per bucket)
    k_verts<<<gW, BS, 0, stream>>>(pos, sdf, scat_base, cnt, rank_base, pool_b,
                                   o_verts, o_vvalid, N);

    // 9. faces via idx_map
    k_faces<<<gF, BS, 0, stream>>>(tet, sdf, rank_base, idx_map, o_faces, o_fvalid, F);
}